// Round 2
// baseline (78.371 us; speedup 1.0000x reference)
//
#include <hip/hip_runtime.h>
#include <math.h>

#define B_   8
#define C_   4
#define H_   96
#define W_   96
#define HW_  9216
#define NBINS 18052     // exact d2 values 0..18050, plus bin 18051 == +inf
#define INFBIN 18051
#define NH32 ((NBINS + 1) / 2)   // 9026 packed words, 2 x u16 counters each
#define G2_SENTINEL 40000        // > 18050, fits u16; marks "row has no target px"

// One block per (b, c, dir). dir==0: fwd (query = pred set, target = label set)
//                            dir==1: rev (query = label set, target = pred set)
__global__ __launch_bounds__(256) void hd_main(const float* __restrict__ preds,
                                               const int*   __restrict__ labels,
                                               float* __restrict__ frws)
{
    __shared__ unsigned long long tmask[HW_ / 64];   // 1152 B target mask bits
    __shared__ unsigned short g2u[HW_];              // 18432 B per-row 1D dist^2 (u16)
    __shared__ unsigned int   h32[NH32];             // 36104 B packed 16-bit histogram
    __shared__ int partials[256];                    // 1024 B
    __shared__ int nT, nQ, svlo, svhi;

    const int id  = blockIdx.x;       // 0..63
    const int dir = id & 1;
    const int bc  = id >> 1;
    const int b   = bc >> 2;
    const int c   = bc & 3;
    const int tid = threadIdx.x;
    const int lane = tid & 63;

    const float* Pb = preds  + (size_t)b * C_ * HW_;
    const int*   Lb = labels + (size_t)b * HW_;

    for (int i = tid; i < NH32; i += 256) h32[i] = 0u;
    if (tid == 0) { nT = 0; nQ = 0; svlo = -1; svhi = -1; }
    __syncthreads();

    // ---- Step 1: build target mask bits (+ count) ----
    for (int k = 0; k < HW_ / 256; ++k) {
        const int p = k * 256 + tid;
        bool m;
        if (dir == 0) {
            m = (Lb[p] == c);
        } else {
            float v0 = Pb[p];
            float v1 = Pb[HW_ + p];
            float v2 = Pb[2 * HW_ + p];
            float v3 = Pb[3 * HW_ + p];
            int bi = 0; float bv = v0;
            if (v1 > bv) { bv = v1; bi = 1; }   // strict '>' keeps first max (jnp.argmax)
            if (v2 > bv) { bv = v2; bi = 2; }
            if (v3 > bv) { bv = v3; bi = 3; }
            m = (bi == c);
        }
        unsigned long long bal = __ballot(m);
        if (lane == 0) {
            tmask[p >> 6] = bal;
            if (bal) atomicAdd(&nT, __popcll(bal));
        }
    }
    __syncthreads();

    // ---- Step 2: horizontal 1D distance per row, store squared (u16) ----
    if (tid < H_) {
        const int base = tid * W_;
        unsigned short tmp[W_];
        int d = 1000;                                    // "no pixel yet" sentinel
        for (int x = 0; x < W_; ++x) {
            const int p = base + x;
            const int bit = (int)((tmask[p >> 6] >> (p & 63)) & 1ull);
            d = bit ? 0 : d + 1;
            tmp[x] = (unsigned short)d;
        }
        d = 1000;
        for (int x = W_ - 1; x >= 0; --x) {
            const int p = base + x;
            const int bit = (int)((tmask[p >> 6] >> (p & 63)) & 1ull);
            d = bit ? 0 : d + 1;
            const int g = min((int)tmp[x], d);
            g2u[p] = (g >= 1000) ? (unsigned short)G2_SENTINEL
                                 : (unsigned short)(g * g);   // g <= 95 -> g2 <= 9025
        }
    }
    __syncthreads();

    const int tEmpty = (nT == 0);

    // ---- Step 3: for every pixel, d2 = min_r (y-r)^2 + g2[r][x]; histogram masked ----
    int myn = 0;
    for (int k = 0; k < HW_ / 256; ++k) {
        const int p = k * 256 + tid;
        bool qm;
        if (dir == 0) {
            float v0 = Pb[p];
            float v1 = Pb[HW_ + p];
            float v2 = Pb[2 * HW_ + p];
            float v3 = Pb[3 * HW_ + p];
            int bi = 0; float bv = v0;
            if (v1 > bv) { bv = v1; bi = 1; }
            if (v2 > bv) { bv = v2; bi = 2; }
            if (v3 > bv) { bv = v3; bi = 3; }
            qm = (bi == c);
        } else {
            qm = (Lb[p] == c);
        }
        const int y = p / W_;
        const int x = p - y * W_;
        int best = 0x7fffffff;
        int dy = y;
        const unsigned short* gp = g2u + x;
        #pragma unroll 8
        for (int r = 0; r < H_; ++r) {
            const int d2 = dy * dy + (int)gp[r * W_];
            best = min(best, d2);
            --dy;
        }
        if (qm) {
            ++myn;
            const int bin = tEmpty ? INFBIN : best;      // best <= 18050 when nT > 0
            atomicAdd(&h32[bin >> 1], 1u << ((bin & 1) << 4));  // 16-bit packed count
        }
    }
    if (myn) atomicAdd(&nQ, myn);
    __syncthreads();

    // ---- Step 4: exact rank selection from histogram ----
    const int n = nQ;
    const int CHUNK = (NBINS + 255) / 256;               // 71
    const int base_i = tid * CHUNK;
    int lsum = 0;
    for (int j = 0; j < CHUNK; ++j) {
        const int i = base_i + j;
        if (i < NBINS) lsum += (int)((h32[i >> 1] >> ((i & 1) << 4)) & 0xFFFFu);
    }
    partials[tid] = lsum;
    __syncthreads();
    if (tid == 0) {
        int run = 0;
        for (int t = 0; t < 256; ++t) { const int v = partials[t]; partials[t] = run; run += v; }
    }
    __syncthreads();

    int nm1 = n - 1; if (nm1 < 0) nm1 = 0;
    const float posf = 0.95f * (float)nm1;               // matches (q/100)*f32(n-1)
    const int lo = (int)floorf(posf);
    const int hi = (int)ceilf(posf);
    const float frac = posf - (float)lo;

    int run = partials[tid];
    for (int j = 0; j < CHUNK; ++j) {
        const int i = base_i + j;
        if (i >= NBINS) break;
        const int h = (int)((h32[i >> 1] >> ((i & 1) << 4)) & 0xFFFFu);
        if (h > 0) {
            const int nrun = run + h;
            if (run <= lo && lo < nrun) svlo = i;        // exactly one thread hits each
            if (run <= hi && hi < nrun) svhi = i;
            run = nrun;
        }
    }
    __syncthreads();

    if (tid == 0) {
        const float vlo = (svlo < 0 || svlo == INFBIN) ? __builtin_inff()
                                                       : (float)sqrt((double)svlo);
        const float vhi = (svhi < 0 || svhi == INFBIN) ? __builtin_inff()
                                                       : (float)sqrt((double)svhi);
        // literal reference arithmetic (inf*0 -> nan semantics preserved)
        frws[id] = vlo * (1.0f - frac) + vhi * frac;
    }
}

__global__ void hd_fin(const float* __restrict__ frws, float* __restrict__ out)
{
    if (blockIdx.x == 0 && threadIdx.x == 0) {
        float F[4], R[4], M[4];
        for (int c = 0; c < 4; ++c) {
            if (c == 0) { F[c] = R[c] = M[c] = 0.0f; continue; }  // IGNORE class
            float sf = 0.0f, sr = 0.0f, sm = 0.0f;
            for (int b = 0; b < 8; ++b) {
                const float f = frws[((b * 4 + c) << 1) + 0];
                const float r = frws[((b * 4 + c) << 1) + 1];
                sf += f; sr += r;
                float m = f > r ? f : r;
                if (f != f || r != r) m = f + r;        // NaN-propagating maximum
                sm += m;
            }
            F[c] = sf / 8.0f; R[c] = sr / 8.0f; M[c] = sm / 8.0f;
        }
        // out = concat(MHD, FHD, RHD), each [c0..c3, mean(all), mean(excl c0)]
        float* o = out;
        o[0] = M[0]; o[1] = M[1]; o[2] = M[2]; o[3] = M[3];
        o[4] = (M[0] + M[1] + M[2] + M[3]) / 4.0f;
        o[5] = (M[1] + M[2] + M[3]) / 3.0f;
        o += 6;
        o[0] = F[0]; o[1] = F[1]; o[2] = F[2]; o[3] = F[3];
        o[4] = (F[0] + F[1] + F[2] + F[3]) / 4.0f;
        o[5] = (F[1] + F[2] + F[3]) / 3.0f;
        o += 6;
        o[0] = R[0]; o[1] = R[1]; o[2] = R[2]; o[3] = R[3];
        o[4] = (R[0] + R[1] + R[2] + R[3]) / 4.0f;
        o[5] = (R[1] + R[2] + R[3]) / 3.0f;
    }
}

extern "C" void kernel_launch(void* const* d_in, const int* in_sizes, int n_in,
                              void* d_out, int out_size, void* d_ws, size_t ws_size,
                              hipStream_t stream)
{
    const float* preds  = (const float*)d_in[0];
    const int*   labels = (const int*)d_in[1];
    float* frws = (float*)d_ws;                  // 64 floats staging (f,r per b,c)

    hipLaunchKernelGGL(hd_main, dim3(B_ * C_ * 2), dim3(256), 0, stream,
                       preds, labels, frws);
    hipLaunchKernelGGL(hd_fin, dim3(1), dim3(64), 0, stream,
                       frws, (float*)d_out);
}

// Round 4
// 51.956 us; speedup vs baseline: 1.5084x; 1.5084x over previous
//
#include <hip/hip_runtime.h>
#include <math.h>

#define B_   8
#define C_   4
#define H_   96
#define W_   96
#define HW_  9216
#define NBINS 18052              // exact d2 values 0..18050, plus bin 18051 == +inf
#define INFBIN 18051
#define NH32 ((NBINS + 1) / 2)   // 9026 packed words, 2 x u16 counters each

// One block per (b, c, dir). dir==0: fwd (query = pred set, target = label set)
//                            dir==1: rev (query = label set, target = pred set)
__global__ __launch_bounds__(256) void hd_main(const float* __restrict__ preds,
                                               const int*   __restrict__ labels,
                                               float* __restrict__ frws)
{
    __shared__ unsigned long long qmask[HW_ / 64];   // 1152 B query mask bits
    __shared__ unsigned long long tmask[HW_ / 64];   // 1152 B target mask bits
    __shared__ unsigned short g2u[HW_];              // 18432 B per-row 1D dist^2 (u16)
    __shared__ unsigned int   h32[NH32];             // 36104 B packed 16-bit histogram
    __shared__ int partials[256];                    // 1024 B
    __shared__ int sc[5];                            // nT, nQ, n0, svlo, svhi

    const int id  = blockIdx.x;       // 0..63
    const int dir = id & 1;
    const int bc  = id >> 1;
    const int b   = bc >> 2;
    const int c   = bc & 3;
    const int tid = threadIdx.x;
    const int lane = tid & 63;

    const float* Pb = preds  + (size_t)b * C_ * HW_;
    const int*   Lb = labels + (size_t)b * HW_;

    for (int i = tid; i < NH32; i += 256) h32[i] = 0u;
    if (tid == 0) { sc[0] = 0; sc[1] = 0; sc[2] = 0; sc[3] = -1; sc[4] = -1; }
    __syncthreads();

    // ---- Step 1: fused argmax + both masks (+ counts, + |q ∩ t| = d2==0 count) ----
    {
        int myT = 0, myQ = 0, myN0 = 0;
        for (int k = 0; k < HW_ / 256; ++k) {
            const int p = k * 256 + tid;
            float v0 = Pb[p];
            float v1 = Pb[HW_ + p];
            float v2 = Pb[2 * HW_ + p];
            float v3 = Pb[3 * HW_ + p];
            int bi = 0; float bv = v0;
            if (v1 > bv) { bv = v1; bi = 1; }   // strict '>' keeps first max (jnp.argmax)
            if (v2 > bv) { bv = v2; bi = 2; }
            if (v3 > bv) { bv = v3; bi = 3; }
            const int lab = Lb[p];
            const bool pm = (bi == c);          // predicted-class mask
            const bool lm = (lab == c);         // label-class mask
            const bool qm = dir ? lm : pm;
            const bool tm = dir ? pm : lm;
            const unsigned long long qb = __ballot(qm);
            const unsigned long long tb = __ballot(tm);
            if (lane == 0) {
                qmask[p >> 6] = qb;
                tmask[p >> 6] = tb;
                myQ  += __popcll(qb);
                myT  += __popcll(tb);
                myN0 += __popcll(qb & tb);      // query pixels with d2 == 0
            }
        }
        if (lane == 0) {
            if (myT)  atomicAdd(&sc[0], myT);
            if (myQ)  atomicAdd(&sc[1], myQ);
            if (myN0) atomicAdd(&sc[2], myN0);
        }
    }
    __syncthreads();

    const int tEmpty = (sc[0] == 0);

    // ---- Step 2: horizontal 1D distance per row, squared u16 (sentinel 40000) ----
    if (tid < H_) {
        const int base = tid * W_;
        unsigned short tmp[W_];
        int d = 1000;                                    // "no pixel yet"
        for (int x = 0; x < W_; ++x) {
            const int p = base + x;
            const int bit = (int)((tmask[p >> 6] >> (p & 63)) & 1ull);
            d = bit ? 0 : d + 1;
            tmp[x] = (unsigned short)d;
        }
        d = 1000;
        for (int x = W_ - 1; x >= 0; --x) {
            const int p = base + x;
            const int bit = (int)((tmask[p >> 6] >> (p & 63)) & 1ull);
            d = bit ? 0 : d + 1;
            const int g = min((int)tmp[x], d);
            g2u[p] = (g >= 96) ? (unsigned short)40000   // row empty: > any real d2
                               : (unsigned short)(g * g);
        }
    }
    __syncthreads();

    // ---- Step 3: exact outward early-exit column scan, query pixels only ----
    // d2(y,x) = min_r (y-r)^2 + g2(r,x). Scanning off = |y-r| outward, once
    // off^2 >= best no farther row can improve (g2 >= 0) -> exact early exit.
    // If target nonempty, some row has g2 <= 95^2, so best <= 18050 and the
    // 40000 sentinel of empty rows never wins.
    for (int k = 0; k < HW_ / 256; ++k) {
        const int p = k * 256 + tid;
        const int qbit = (int)((qmask[p >> 6] >> (p & 63)) & 1ull);
        if (!qbit) continue;
        if (tEmpty) {
            atomicAdd(&h32[INFBIN >> 1], 1u << ((INFBIN & 1) << 4));
            continue;
        }
        const int tbit = (int)((tmask[p >> 6] >> (p & 63)) & 1ull);
        if (tbit) continue;                              // d2 == 0, counted via popcount
        const int y = p / W_;
        const int x = p - y * W_;
        int best = (int)g2u[p];                          // off = 0 row
        for (int off = 1; off < H_; ++off) {
            const int o2 = off * off;
            if (o2 >= best) break;
            const int r1 = y - off;
            const int r2 = y + off;
            if (r1 >= 0) best = min(best, o2 + (int)g2u[r1 * W_ + x]);
            if (r2 < H_) best = min(best, o2 + (int)g2u[r2 * W_ + x]);
        }
        atomicAdd(&h32[best >> 1], 1u << ((best & 1) << 4));  // best in [1, 18050]
    }
    __syncthreads();

    if (tid == 0 && !tEmpty && sc[2] > 0)
        h32[0] += (unsigned int)sc[2];                   // bin 0 lives in low half of word 0
    __syncthreads();

    // ---- Step 4: exact rank selection from packed histogram ----
    const int n = sc[1];
    const int CHUNK = (NBINS + 255) / 256;               // 71
    const int base_i = tid * CHUNK;
    int lsum = 0;
    for (int j = 0; j < CHUNK; ++j) {
        const int i = base_i + j;
        if (i < NBINS) lsum += (int)((h32[i >> 1] >> ((i & 1) << 4)) & 0xFFFFu);
    }
    partials[tid] = lsum;
    __syncthreads();
    if (tid == 0) {
        int run = 0;
        for (int t = 0; t < 256; ++t) { const int v = partials[t]; partials[t] = run; run += v; }
    }
    __syncthreads();

    int nm1 = n - 1; if (nm1 < 0) nm1 = 0;
    const float posf = 0.95f * (float)nm1;               // matches (q/100)*f32(n-1)
    const int lo = (int)floorf(posf);
    const int hi = (int)ceilf(posf);
    const float frac = posf - (float)lo;

    int run = partials[tid];
    for (int j = 0; j < CHUNK; ++j) {
        const int i = base_i + j;
        if (i >= NBINS) break;
        const int h = (int)((h32[i >> 1] >> ((i & 1) << 4)) & 0xFFFFu);
        if (h > 0) {
            const int nrun = run + h;
            if (run <= lo && lo < nrun) sc[3] = i;       // exactly one thread hits each
            if (run <= hi && hi < nrun) sc[4] = i;
            run = nrun;
        }
    }
    __syncthreads();

    if (tid == 0) {
        const int svlo = sc[3], svhi = sc[4];
        const float vlo = (svlo < 0 || svlo == INFBIN) ? __builtin_inff()
                                                       : (float)sqrt((double)svlo);
        const float vhi = (svhi < 0 || svhi == INFBIN) ? __builtin_inff()
                                                       : (float)sqrt((double)svhi);
        // literal reference arithmetic (inf*0 -> nan semantics preserved)
        frws[id] = vlo * (1.0f - frac) + vhi * frac;
    }
}

__global__ void hd_fin(const float* __restrict__ frws, float* __restrict__ out)
{
    if (blockIdx.x == 0 && threadIdx.x == 0) {
        float F[4], R[4], M[4];
        for (int c = 0; c < 4; ++c) {
            if (c == 0) { F[c] = R[c] = M[c] = 0.0f; continue; }  // IGNORE class
            float sf = 0.0f, sr = 0.0f, sm = 0.0f;
            for (int b = 0; b < 8; ++b) {
                const float f = frws[((b * 4 + c) << 1) + 0];
                const float r = frws[((b * 4 + c) << 1) + 1];
                sf += f; sr += r;
                float m = f > r ? f : r;
                if (f != f || r != r) m = f + r;        // NaN-propagating maximum
                sm += m;
            }
            F[c] = sf / 8.0f; R[c] = sr / 8.0f; M[c] = sm / 8.0f;
        }
        // out = concat(MHD, FHD, RHD), each [c0..c3, mean(all), mean(excl c0)]
        float* o = out;
        o[0] = M[0]; o[1] = M[1]; o[2] = M[2]; o[3] = M[3];
        o[4] = (M[0] + M[1] + M[2] + M[3]) / 4.0f;
        o[5] = (M[1] + M[2] + M[3]) / 3.0f;
        o += 6;
        o[0] = F[0]; o[1] = F[1]; o[2] = F[2]; o[3] = F[3];
        o[4] = (F[0] + F[1] + F[2] + F[3]) / 4.0f;
        o[5] = (F[1] + F[2] + F[3]) / 3.0f;
        o += 6;
        o[0] = R[0]; o[1] = R[1]; o[2] = R[2]; o[3] = R[3];
        o[4] = (R[0] + R[1] + R[2] + R[3]) / 4.0f;
        o[5] = (R[1] + R[2] + R[3]) / 3.0f;
    }
}

extern "C" void kernel_launch(void* const* d_in, const int* in_sizes, int n_in,
                              void* d_out, int out_size, void* d_ws, size_t ws_size,
                              hipStream_t stream)
{
    const float* preds  = (const float*)d_in[0];
    const int*   labels = (const int*)d_in[1];
    float* frws = (float*)d_ws;                  // 64 floats staging (f,r per b,c)

    hipLaunchKernelGGL(hd_main, dim3(B_ * C_ * 2), dim3(256), 0, stream,
                       preds, labels, frws);
    hipLaunchKernelGGL(hd_fin, dim3(1), dim3(64), 0, stream,
                       frws, (float*)d_out);
}